// Round 3
// baseline (224.520 us; speedup 1.0000x reference)
//
#include <hip/hip_runtime.h>
#include <math.h>

#define Bb 2
#define Ss 128
#define Hh 768
#define Cc 5
#define NT 4608      // Hh + Cc*Hh
#define Mm 256       // Bb*Ss
#define NEGV -1024.0f
#define SCALE 2.8853900817779268f   // 2/ln(2): Hall pre-scaled so exp2(hp'+ha') = e^{2x}

typedef __attribute__((ext_vector_type(8))) short bf16x8;
typedef __attribute__((ext_vector_type(4))) float f32x4;

// ---------------- Kernel 1: bf16 MFMA GEMM  Hall = SCALE*(X.Wcat^T + bias) ----------------
__device__ __forceinline__ unsigned pack_hi16(float hi, float lo) {
    return (__float_as_uint(hi) & 0xFFFF0000u) | (__float_as_uint(lo) >> 16);
}

__device__ __forceinline__ bf16x8 pack_bf16x8(float4 lo, float4 hi) {
    union { bf16x8 v; unsigned u[4]; } r;
    r.u[0] = pack_hi16(lo.y, lo.x);
    r.u[1] = pack_hi16(lo.w, lo.z);
    r.u[2] = pack_hi16(hi.y, hi.x);
    r.u[3] = pack_hi16(hi.w, hi.z);
    return r.v;
}

__global__ __launch_bounds__(256)
void gemm_mfma(const float* __restrict__ X,
               const float* __restrict__ Wprd,
               const float* __restrict__ Warg,
               const float* __restrict__ bprd,
               const float* __restrict__ barg,
               float* __restrict__ Hall)
{
    const int bm   = blockIdx.x;          // 0..3   (64 rows)
    const int bn   = blockIdx.y;          // 0..143 (32 cols)
    const int wave = threadIdx.x >> 6;    // 0..3
    const int lane = threadIdx.x & 63;
    const int l16  = lane & 15;
    const int quad = lane >> 4;

    const float* Wsrc; const float* bsrc;
    const int nb = bn * 32;
    if (nb < Hh) { Wsrc = Wprd + (size_t)nb * Hh;        bsrc = bprd + nb; }
    else         { Wsrc = Warg + (size_t)(nb - Hh) * Hh; bsrc = barg + (nb - Hh); }

    const int m_g = bm * 64 + wave * 16 + l16;
    const float* arow  = X    + (size_t)m_g * Hh + quad * 8;
    const float* brow0 = Wsrc + (size_t)l16 * Hh + quad * 8;
    const float* brow1 = Wsrc + (size_t)(16 + l16) * Hh + quad * 8;

    f32x4 acc0 = {0.f, 0.f, 0.f, 0.f};
    f32x4 acc1 = {0.f, 0.f, 0.f, 0.f};

    // software pipeline: keep next iteration's 6 loads in flight during MFMA
    float4 a0  = *(const float4*)(arow);
    float4 a1  = *(const float4*)(arow + 4);
    float4 b00 = *(const float4*)(brow0);
    float4 b01 = *(const float4*)(brow0 + 4);
    float4 b10 = *(const float4*)(brow1);
    float4 b11 = *(const float4*)(brow1 + 4);

    #pragma unroll 4
    for (int k = 0; k < Hh; k += 32) {
        const int kn = (k + 32 < Hh) ? k + 32 : 0;   // last iter reloads k=0 (harmless)
        float4 na0  = *(const float4*)(arow  + kn);
        float4 na1  = *(const float4*)(arow  + kn + 4);
        float4 nb00 = *(const float4*)(brow0 + kn);
        float4 nb01 = *(const float4*)(brow0 + kn + 4);
        float4 nb10 = *(const float4*)(brow1 + kn);
        float4 nb11 = *(const float4*)(brow1 + kn + 4);
        bf16x8 af  = pack_bf16x8(a0,  a1);
        bf16x8 bf0 = pack_bf16x8(b00, b01);
        bf16x8 bf1 = pack_bf16x8(b10, b11);
        acc0 = __builtin_amdgcn_mfma_f32_16x16x32_bf16(af, bf0, acc0, 0, 0, 0);
        acc1 = __builtin_amdgcn_mfma_f32_16x16x32_bf16(af, bf1, acc1, 0, 0, 0);
        a0 = na0; a1 = na1; b00 = nb00; b01 = nb01; b10 = nb10; b11 = nb11;
    }

    const float sb0 = SCALE * bsrc[l16];
    const float sb1 = SCALE * bsrc[16 + l16];
    const int row  = bm * 64 + wave * 16 + quad * 4;
    const int col0 = nb + l16;
    const int col1 = nb + 16 + l16;
    #pragma unroll
    for (int r = 0; r < 4; ++r) {
        Hall[(size_t)(row + r) * NT + col0] = SCALE * acc0[r] + sb0;
        Hall[(size_t)(row + r) * NT + col1] = SCALE * acc1[r] + sb1;
    }
}

// ---------------- Kernel 2: biaffine + mask + logits + log-softmax + loss ----------------
// One block per (b,p); 640 threads = one per (c,a). Hall pre-scaled by 2/ln2.
// logit = sumW[c] - 2 * sum_h w[c,h] * rcp(exp2(hp'+ha') + 1)   (tanh = 1 - 2/(e^2x+1))
// hp row and w row are wave-uniform -> scalar (SGPR) loads; ha double-buffered in VGPRs.
__global__ __launch_bounds__(640)
void biaffine_loss(const float* __restrict__ Hall,
                   const float* __restrict__ Wout,
                   const int* __restrict__ ng,
                   const int* __restrict__ att,
                   const float* __restrict__ target,
                   float* __restrict__ out_logits,  // d_out + 1
                   float* __restrict__ accum)       // {num, den}
{
    __shared__ float maskneg[Ss];
    __shared__ float redmax[Cc][2];
    __shared__ float red3[Cc][2][3];

    const int bp  = blockIdx.x;      // b*128 + p
    const int b   = bp >> 7;
    const int tid = threadIdx.x;

    if (tid < Ss) {
        const int aa = tid;
        int any = 0;
        if (att[b * Ss + aa] > 0) {
            const int* ngp = ng + (size_t)bp * Cc * Ss + aa;
            #pragma unroll
            for (int cc = 0; cc < Cc; ++cc) any |= ngp[cc * Ss];
        }
        maskneg[aa] = any ? 0.0f : NEGV;
    }
    __syncthreads();

    const int c    = __builtin_amdgcn_readfirstlane(tid >> 7);  // wave-uniform -> SGPR
    const int a    = tid & (Ss - 1);
    const int lane = tid & 63;
    const float* hp  = Hall + (size_t)bp * NT;                  // block-uniform
    const float* wc  = Wout + (size_t)c * Hh;                   // wave-uniform
    const float* hap = Hall + (size_t)(b * Ss + a) * NT + Hh + (size_t)c * Hh;

    // sumW[c] = sum of the wave's W_out row (all lanes end with the value)
    float sw = 0.f;
    for (int i = lane; i < Hh; i += 64) sw += wc[i];
    #pragma unroll
    for (int off = 32; off; off >>= 1) sw += __shfl_xor(sw, off, 64);

    float4 g[8], m[8];
    #pragma unroll
    for (int j = 0; j < 8; ++j) g[j] = *(const float4*)(hap + j * 4);

    float ac0 = 0.f, ac1 = 0.f, ac2 = 0.f, ac3 = 0.f;
    for (int h = 0; h < Hh; h += 32) {
        const int hn = (h + 32 < Hh) ? h + 32 : 0;   // clamp: no OOB, last prefetch harmless
        #pragma unroll
        for (int j = 0; j < 8; ++j) m[j] = *(const float4*)(hap + hn + j * 4);
        #pragma unroll
        for (int j = 0; j < 8; ++j) {
            float4 p = *(const float4*)(hp + h + j * 4);   // scalar loads (SGPR)
            float4 w = *(const float4*)(wc + h + j * 4);   // scalar loads (SGPR)
            float r0 = __builtin_amdgcn_rcpf(__builtin_amdgcn_exp2f(p.x + g[j].x) + 1.0f);
            float r1 = __builtin_amdgcn_rcpf(__builtin_amdgcn_exp2f(p.y + g[j].y) + 1.0f);
            float r2 = __builtin_amdgcn_rcpf(__builtin_amdgcn_exp2f(p.z + g[j].z) + 1.0f);
            float r3 = __builtin_amdgcn_rcpf(__builtin_amdgcn_exp2f(p.w + g[j].w) + 1.0f);
            ac0 = fmaf(w.x, r0, ac0);
            ac1 = fmaf(w.y, r1, ac1);
            ac2 = fmaf(w.z, r2, ac2);
            ac3 = fmaf(w.w, r3, ac3);
        }
        #pragma unroll
        for (int j = 0; j < 8; ++j) g[j] = m[j];
    }
    const float logit = sw - 2.0f * ((ac0 + ac1) + (ac2 + ac3)) + maskneg[a];
    out_logits[((size_t)bp * Cc + c) * Ss + a] = logit;

    // ---- log-softmax over a (row = (bp,c): 128 entries = 2 waves) + loss terms ----
    const int half = a >> 6;
    float mx = logit;
    #pragma unroll
    for (int off = 32; off > 0; off >>= 1)
        mx = fmaxf(mx, __shfl_xor(mx, off, 64));
    if (lane == 0) redmax[c][half] = mx;
    __syncthreads();
    const float rm = fmaxf(redmax[c][0], redmax[c][1]);

    const float e  = __builtin_amdgcn_exp2f((logit - rm) * 1.4426950408889634f);
    const float tg = target[((size_t)bp * Cc + c) * Ss + a];
    float se = e, st = tg, sx = tg * logit;
    #pragma unroll
    for (int off = 32; off > 0; off >>= 1) {
        se += __shfl_xor(se, off, 64);
        st += __shfl_xor(st, off, 64);
        sx += __shfl_xor(sx, off, 64);
    }
    if (lane == 0) { red3[c][half][0] = se; red3[c][half][1] = st; red3[c][half][2] = sx; }
    __syncthreads();
    if (a == 0) {
        const float SE = red3[c][0][0] + red3[c][1][0];
        const float ST = red3[c][0][1] + red3[c][1][1];
        const float SX = red3[c][0][2] + red3[c][1][2];
        const float lse = rm + __builtin_amdgcn_logf(SE) * 0.6931471805599453f;
        atomicAdd(&accum[0], lse * ST - SX);   // sum target*(lse - x)
        atomicAdd(&accum[1], ST);              // sum target
    }
}

__global__ void finalize_loss(const float* __restrict__ accum, float* __restrict__ out)
{
    out[0] = accum[0] / accum[1];
}

extern "C" void kernel_launch(void* const* d_in, const int* in_sizes, int n_in,
                              void* d_out, int out_size, void* d_ws, size_t ws_size,
                              hipStream_t stream) {
    const float* seq    = (const float*)d_in[0];
    const int*   att    = (const int*)  d_in[1];
    const int*   ng     = (const int*)  d_in[2];
    const float* target = (const float*)d_in[3];
    const float* Wprd   = (const float*)d_in[4];
    const float* bprd   = (const float*)d_in[5];
    const float* Warg   = (const float*)d_in[6];
    const float* barg   = (const float*)d_in[7];
    const float* Wout   = (const float*)d_in[8];

    float* out   = (float*)d_out;
    float* Hall  = (float*)d_ws;                     // 256 x 4608 fp32 (pre-scaled by 2/ln2)
    float* accum = Hall + (size_t)Mm * NT;           // 2 floats

    hipMemsetAsync(accum, 0, 2 * sizeof(float), stream);
    gemm_mfma<<<dim3(4, 144), 256, 0, stream>>>(seq, Wprd, Warg, bprd, barg, Hall);
    biaffine_loss<<<dim3(Mm), 640, 0, stream>>>(Hall, Wout, ng, att, target, out + 1, accum);
    finalize_loss<<<1, 1, 0, stream>>>(accum, out);
}

// Round 4
// 200.135 us; speedup vs baseline: 1.1218x; 1.1218x over previous
//
#include <hip/hip_runtime.h>
#include <math.h>

#define Bb 2
#define Ss 128
#define Hh 768
#define Cc 5
#define Mm 256       // Bb*Ss
#define NEGV -1024.0f
#define SCALE 2.8853900817779268f   // 2/ln(2): stored pre-scaled so exp2(hp'+ha') = e^{2x}

// haT layout: [b][c][hg][a][hl], hg=h/4, hl=h&3
#define HA_B  491520   // 5*192*128*4
#define HA_C  98304    // 192*128*4
#define HA_HG 512      // 128*4

typedef __attribute__((ext_vector_type(8))) short bf16x8;
typedef __attribute__((ext_vector_type(4))) float f32x4;

__device__ __forceinline__ unsigned pack_hi16(float hi, float lo) {
    return (__float_as_uint(hi) & 0xFFFF0000u) | (__float_as_uint(lo) >> 16);
}
__device__ __forceinline__ bf16x8 pack_bf16x8(float4 lo, float4 hi) {
    union { bf16x8 v; unsigned u[4]; } r;
    r.u[0] = pack_hi16(lo.y, lo.x);
    r.u[1] = pack_hi16(lo.w, lo.z);
    r.u[2] = pack_hi16(hi.y, hi.x);
    r.u[3] = pack_hi16(hi.w, hi.z);
    return r.v;
}

// ---------------- Kernel 1: bf16 MFMA GEMM -> hp (row-major) + haT (transposed) ----------------
__global__ __launch_bounds__(256)
void gemm_mfma(const float* __restrict__ X,
               const float* __restrict__ Wprd,
               const float* __restrict__ Warg,
               const float* __restrict__ bprd,
               const float* __restrict__ barg,
               float* __restrict__ hp_out,
               float* __restrict__ haT,
               float* __restrict__ accum)
{
    if (blockIdx.x == 0 && blockIdx.y == 0 && threadIdx.x == 0) {
        accum[0] = 0.f; accum[1] = 0.f;   // runs before biaffine (same stream)
    }
    const int bm   = blockIdx.x;          // 0..3   (64 rows)
    const int bn   = blockIdx.y;          // 0..143 (32 cols)
    const int wave = threadIdx.x >> 6;
    const int lane = threadIdx.x & 63;
    const int l16  = lane & 15;
    const int quad = lane >> 4;

    const float* Wsrc; const float* bsrc;
    const int nb = bn * 32;
    if (nb < Hh) { Wsrc = Wprd + (size_t)nb * Hh;        bsrc = bprd + nb; }
    else         { Wsrc = Warg + (size_t)(nb - Hh) * Hh; bsrc = barg + (nb - Hh); }

    const int m_g = bm * 64 + wave * 16 + l16;
    const float* arow  = X    + (size_t)m_g * Hh + quad * 8;
    const float* brow0 = Wsrc + (size_t)l16 * Hh + quad * 8;
    const float* brow1 = Wsrc + (size_t)(16 + l16) * Hh + quad * 8;

    f32x4 acc0 = {0.f, 0.f, 0.f, 0.f};
    f32x4 acc1 = {0.f, 0.f, 0.f, 0.f};

    float4 a0  = *(const float4*)(arow);
    float4 a1  = *(const float4*)(arow + 4);
    float4 b00 = *(const float4*)(brow0);
    float4 b01 = *(const float4*)(brow0 + 4);
    float4 b10 = *(const float4*)(brow1);
    float4 b11 = *(const float4*)(brow1 + 4);

    #pragma unroll 4
    for (int k = 0; k < Hh; k += 32) {
        const int kn = (k + 32 < Hh) ? k + 32 : 0;
        float4 na0  = *(const float4*)(arow  + kn);
        float4 na1  = *(const float4*)(arow  + kn + 4);
        float4 nb00 = *(const float4*)(brow0 + kn);
        float4 nb01 = *(const float4*)(brow0 + kn + 4);
        float4 nb10 = *(const float4*)(brow1 + kn);
        float4 nb11 = *(const float4*)(brow1 + kn + 4);
        bf16x8 af  = pack_bf16x8(a0,  a1);
        bf16x8 bf0 = pack_bf16x8(b00, b01);
        bf16x8 bf1 = pack_bf16x8(b10, b11);
        acc0 = __builtin_amdgcn_mfma_f32_16x16x32_bf16(af, bf0, acc0, 0, 0, 0);
        acc1 = __builtin_amdgcn_mfma_f32_16x16x32_bf16(af, bf1, acc1, 0, 0, 0);
        a0 = na0; a1 = na1; b00 = nb00; b01 = nb01; b10 = nb10; b11 = nb11;
    }

    const float sb0 = SCALE * bsrc[l16];
    const float sb1 = SCALE * bsrc[16 + l16];
    const int row = bm * 64 + wave * 16 + quad * 4;

    if (nb < Hh) {   // hp part: row-major [m][h]
        #pragma unroll
        for (int r = 0; r < 4; ++r) {
            const int mm = row + r;
            hp_out[(size_t)mm * Hh + nb + l16]      = SCALE * acc0[r] + sb0;
            hp_out[(size_t)mm * Hh + nb + 16 + l16] = SCALE * acc1[r] + sb1;
        }
    } else {         // ha part -> haT[b][c][hg][a][hl]  (32-col tile never straddles c)
        const int q  = nb - Hh;
        const int cU = q / Hh;
        const int h0 = q % Hh;
        const int off0 = cU * HA_C + ((h0 + l16) >> 2) * HA_HG + (l16 & 3);
        const int off1 = off0 + 4 * HA_HG;   // +16 h
        #pragma unroll
        for (int r = 0; r < 4; ++r) {
            const int mm = row + r;
            const int base = (mm >> 7) * HA_B + (mm & 127) * 4;
            haT[base + off0] = SCALE * acc0[r] + sb0;
            haT[base + off1] = SCALE * acc1[r] + sb1;
        }
    }
}

// ---------------- Kernel 2: biaffine + mask + logits + log-softmax + loss ----------------
// Block per (b,p); 640 thr = (c,a). ha loads now lane-coalesced via haT.
// logit = sumW[c] - 2 * sum_h w[c,h]*rcp(exp2(hp'+ha')+1) + maskneg
__global__ __launch_bounds__(640)
void biaffine_loss(const float* __restrict__ hp_all,
                   const float* __restrict__ haT,
                   const float* __restrict__ Wout,
                   const int* __restrict__ ng,
                   const int* __restrict__ att,
                   const float* __restrict__ target,
                   float* __restrict__ out_logits,
                   float* __restrict__ accum)
{
    __shared__ float maskneg[Ss];
    __shared__ float redmax[Cc][2];
    __shared__ float red3[Cc][2][3];

    const int bp  = blockIdx.x;
    const int b   = bp >> 7;
    const int tid = threadIdx.x;

    const int c    = __builtin_amdgcn_readfirstlane(tid >> 7);
    const int a    = tid & (Ss - 1);
    const int lane = tid & 63;
    const float* hp  = hp_all + (size_t)bp * Hh;                       // block-uniform
    const float* wc  = Wout + (size_t)c * Hh;                          // wave-uniform
    const float* haP = haT + (size_t)b * HA_B + (size_t)c * HA_C + a * 4;

    float4 g[4], m[4];
    #pragma unroll
    for (int j = 0; j < 4; ++j) g[j] = *(const float4*)(haP + j * HA_HG);

    if (tid < Ss) {
        const int aa = tid;
        int any = 0;
        if (att[b * Ss + aa] > 0) {
            const int* ngp = ng + (size_t)bp * Cc * Ss + aa;
            #pragma unroll
            for (int cc = 0; cc < Cc; ++cc) any |= ngp[cc * Ss];
        }
        maskneg[aa] = any ? 0.0f : NEGV;
    }
    __syncthreads();

    // sumW[c]
    float sw = 0.f;
    for (int i = lane; i < Hh; i += 64) sw += wc[i];
    #pragma unroll
    for (int off = 32; off; off >>= 1) sw += __shfl_xor(sw, off, 64);

    float ac0 = 0.f, ac1 = 0.f, ac2 = 0.f, ac3 = 0.f;
    for (int h = 0; h < Hh; h += 16) {
        const int hgn = (h + 16 < Hh) ? (h + 16) >> 2 : 0;
        #pragma unroll
        for (int j = 0; j < 4; ++j) m[j] = *(const float4*)(haP + (hgn + j) * HA_HG);
        #pragma unroll
        for (int j = 0; j < 4; ++j) {
            float4 p = *(const float4*)(hp + h + j * 4);   // scalar (uniform)
            float4 w = *(const float4*)(wc + h + j * 4);   // scalar (uniform)
            float r0 = __builtin_amdgcn_rcpf(__builtin_amdgcn_exp2f(p.x + g[j].x) + 1.0f);
            float r1 = __builtin_amdgcn_rcpf(__builtin_amdgcn_exp2f(p.y + g[j].y) + 1.0f);
            float r2 = __builtin_amdgcn_rcpf(__builtin_amdgcn_exp2f(p.z + g[j].z) + 1.0f);
            float r3 = __builtin_amdgcn_rcpf(__builtin_amdgcn_exp2f(p.w + g[j].w) + 1.0f);
            ac0 = fmaf(w.x, r0, ac0);
            ac1 = fmaf(w.y, r1, ac1);
            ac2 = fmaf(w.z, r2, ac2);
            ac3 = fmaf(w.w, r3, ac3);
        }
        #pragma unroll
        for (int j = 0; j < 4; ++j) g[j] = m[j];
    }
    const float logit = sw - 2.0f * ((ac0 + ac1) + (ac2 + ac3)) + maskneg[a];
    out_logits[((size_t)bp * Cc + c) * Ss + a] = logit;

    // log-softmax over a (row = (bp,c)) + loss terms
    const int half = a >> 6;
    float mx = logit;
    #pragma unroll
    for (int off = 32; off > 0; off >>= 1)
        mx = fmaxf(mx, __shfl_xor(mx, off, 64));
    if (lane == 0) redmax[c][half] = mx;
    __syncthreads();
    const float rm = fmaxf(redmax[c][0], redmax[c][1]);

    const float e  = __builtin_amdgcn_exp2f((logit - rm) * 1.4426950408889634f);
    const float tg = target[((size_t)bp * Cc + c) * Ss + a];
    float se = e, st = tg, sx = tg * logit;
    #pragma unroll
    for (int off = 32; off > 0; off >>= 1) {
        se += __shfl_xor(se, off, 64);
        st += __shfl_xor(st, off, 64);
        sx += __shfl_xor(sx, off, 64);
    }
    if (lane == 0) { red3[c][half][0] = se; red3[c][half][1] = st; red3[c][half][2] = sx; }
    __syncthreads();
    if (a == 0) {
        const float SE = red3[c][0][0] + red3[c][1][0];
        const float ST = red3[c][0][1] + red3[c][1][1];
        const float SX = red3[c][0][2] + red3[c][1][2];
        const float lse = rm + __builtin_amdgcn_logf(SE) * 0.6931471805599453f;
        atomicAdd(&accum[0], lse * ST - SX);
        atomicAdd(&accum[1], ST);
    }
}

__global__ void finalize_loss(const float* __restrict__ accum, float* __restrict__ out)
{
    out[0] = accum[0] / accum[1];
}

extern "C" void kernel_launch(void* const* d_in, const int* in_sizes, int n_in,
                              void* d_out, int out_size, void* d_ws, size_t ws_size,
                              hipStream_t stream) {
    const float* seq    = (const float*)d_in[0];
    const int*   att    = (const int*)  d_in[1];
    const int*   ng     = (const int*)  d_in[2];
    const float* target = (const float*)d_in[3];
    const float* Wprd   = (const float*)d_in[4];
    const float* bprd   = (const float*)d_in[5];
    const float* Warg   = (const float*)d_in[6];
    const float* barg   = (const float*)d_in[7];
    const float* Wout   = (const float*)d_in[8];

    float* out    = (float*)d_out;
    float* hp_out = (float*)d_ws;                        // 256*768 floats
    float* haT    = hp_out + (size_t)Mm * Hh;            // 2*491520 floats
    float* accum  = haT + 2 * (size_t)HA_B;              // 2 floats

    gemm_mfma<<<dim3(4, 144), 256, 0, stream>>>(seq, Wprd, Warg, bprd, barg,
                                                hp_out, haT, accum);
    biaffine_loss<<<dim3(Mm), 640, 0, stream>>>(hp_out, haT, Wout, ng, att, target,
                                                out + 1, accum);
    finalize_loss<<<1, 1, 0, stream>>>(accum, out);
}

// Round 5
// 194.703 us; speedup vs baseline: 1.1531x; 1.0279x over previous
//
#include <hip/hip_runtime.h>
#include <math.h>

#define Bb 2
#define Ss 128
#define Hh 768
#define Cc 5
#define Mm 256       // Bb*Ss
#define NEGV -1024.0f
#define SCALE 2.8853900817779268f   // 2/ln(2): stored pre-scaled so exp2(hp'+ha') = e^{2x}

// haT layout: [b][c][hg][a][hl], hg=h/4, hl=h&3
#define HA_B  491520   // 5*192*128*4
#define HA_C  98304    // 192*128*4
#define HA_HG 512      // 128*4

typedef __attribute__((ext_vector_type(8))) short bf16x8;
typedef __attribute__((ext_vector_type(4))) float f32x4;

__device__ __forceinline__ unsigned pack_hi16(float hi, float lo) {
    return (__float_as_uint(hi) & 0xFFFF0000u) | (__float_as_uint(lo) >> 16);
}
__device__ __forceinline__ bf16x8 pack_bf16x8(float4 lo, float4 hi) {
    union { bf16x8 v; unsigned u[4]; } r;
    r.u[0] = pack_hi16(lo.y, lo.x);
    r.u[1] = pack_hi16(lo.w, lo.z);
    r.u[2] = pack_hi16(hi.y, hi.x);
    r.u[3] = pack_hi16(hi.w, hi.z);
    return r.v;
}

// ---------------- Kernel 1: bf16 MFMA GEMM -> hp (row-major) + haT (transposed) ----------------
__global__ __launch_bounds__(256)
void gemm_mfma(const float* __restrict__ X,
               const float* __restrict__ Wprd,
               const float* __restrict__ Warg,
               const float* __restrict__ bprd,
               const float* __restrict__ barg,
               float* __restrict__ hp_out,
               float* __restrict__ haT,
               float* __restrict__ accum)
{
    if (blockIdx.x == 0 && blockIdx.y == 0 && threadIdx.x == 0) {
        accum[0] = 0.f; accum[1] = 0.f;
        ((unsigned*)accum)[2] = 0u;      // completion counter
    }
    const int bm   = blockIdx.x;          // 0..3   (64 rows)
    const int bn   = blockIdx.y;          // 0..143 (32 cols)
    const int wave = threadIdx.x >> 6;
    const int lane = threadIdx.x & 63;
    const int l16  = lane & 15;
    const int quad = lane >> 4;

    const float* Wsrc; const float* bsrc;
    const int nb = bn * 32;
    if (nb < Hh) { Wsrc = Wprd + (size_t)nb * Hh;        bsrc = bprd + nb; }
    else         { Wsrc = Warg + (size_t)(nb - Hh) * Hh; bsrc = barg + (nb - Hh); }

    const int m_g = bm * 64 + wave * 16 + l16;
    const float* arow  = X    + (size_t)m_g * Hh + quad * 8;
    const float* brow0 = Wsrc + (size_t)l16 * Hh + quad * 8;
    const float* brow1 = Wsrc + (size_t)(16 + l16) * Hh + quad * 8;

    f32x4 acc0 = {0.f, 0.f, 0.f, 0.f};
    f32x4 acc1 = {0.f, 0.f, 0.f, 0.f};

    float4 a0  = *(const float4*)(arow);
    float4 a1  = *(const float4*)(arow + 4);
    float4 b00 = *(const float4*)(brow0);
    float4 b01 = *(const float4*)(brow0 + 4);
    float4 b10 = *(const float4*)(brow1);
    float4 b11 = *(const float4*)(brow1 + 4);

    #pragma unroll 4
    for (int k = 0; k < Hh; k += 32) {
        const int kn = (k + 32 < Hh) ? k + 32 : 0;
        float4 na0  = *(const float4*)(arow  + kn);
        float4 na1  = *(const float4*)(arow  + kn + 4);
        float4 nb00 = *(const float4*)(brow0 + kn);
        float4 nb01 = *(const float4*)(brow0 + kn + 4);
        float4 nb10 = *(const float4*)(brow1 + kn);
        float4 nb11 = *(const float4*)(brow1 + kn + 4);
        bf16x8 af  = pack_bf16x8(a0,  a1);
        bf16x8 bf0 = pack_bf16x8(b00, b01);
        bf16x8 bf1 = pack_bf16x8(b10, b11);
        acc0 = __builtin_amdgcn_mfma_f32_16x16x32_bf16(af, bf0, acc0, 0, 0, 0);
        acc1 = __builtin_amdgcn_mfma_f32_16x16x32_bf16(af, bf1, acc1, 0, 0, 0);
        a0 = na0; a1 = na1; b00 = nb00; b01 = nb01; b10 = nb10; b11 = nb11;
    }

    const float sb0 = SCALE * bsrc[l16];
    const float sb1 = SCALE * bsrc[16 + l16];
    const int row = bm * 64 + wave * 16 + quad * 4;

    if (nb < Hh) {   // hp: row-major [m][h]
        #pragma unroll
        for (int r = 0; r < 4; ++r) {
            const int mm = row + r;
            hp_out[(size_t)mm * Hh + nb + l16]      = SCALE * acc0[r] + sb0;
            hp_out[(size_t)mm * Hh + nb + 16 + l16] = SCALE * acc1[r] + sb1;
        }
    } else {         // ha -> haT[b][c][hg][a][hl]
        const int q  = nb - Hh;
        const int cU = q / Hh;
        const int h0 = q % Hh;
        const int off0 = cU * HA_C + ((h0 + l16) >> 2) * HA_HG + (l16 & 3);
        const int off1 = off0 + 4 * HA_HG;
        #pragma unroll
        for (int r = 0; r < 4; ++r) {
            const int mm = row + r;
            const int base = (mm >> 7) * HA_B + (mm & 127) * 4;
            haT[base + off0] = SCALE * acc0[r] + sb0;
            haT[base + off1] = SCALE * acc1[r] + sb1;
        }
    }
}

// ---------------- Kernel 2: biaffine + mask + logits + log-softmax + loss ----------------
// Grid 1280 = (bp, c). Block 256 thr: tid = hh*128 + a; each thread reduces 384 h.
// logit = sumW[c] - 2*sum_h wc[h]*rcp(exp2(hp'+ha')+1) + maskneg[a]
__global__ __launch_bounds__(256, 5)
void biaffine_loss(const float* __restrict__ hp_all,
                   const float* __restrict__ haT,
                   const float* __restrict__ Wout,
                   const int* __restrict__ ng,
                   const int* __restrict__ att,
                   const float* __restrict__ target,
                   float* __restrict__ out_logits,
                   float* __restrict__ accum,
                   float* __restrict__ out_loss)
{
    __shared__ float hp_s[Hh];
    __shared__ float wc_s[Hh];
    __shared__ float partial[Ss];
    __shared__ float maskneg[Ss];
    __shared__ float redmax[2];
    __shared__ float red3[2][3];
    __shared__ float swr_s;

    const int bpc = blockIdx.x;
    const int bp  = bpc / Cc;
    const int c   = bpc - bp * Cc;
    const int b   = bp >> 7;
    const int tid = threadIdx.x;
    const int a   = tid & (Ss - 1);
    const int hh  = tid >> 7;          // 0/1 : h-half (wave-uniform)
    const int lane = tid & 63;
    const int h0  = hh * (Hh / 2);     // 0 or 384

    // start ha fragment loads before the staging barrier (in flight early)
    const float* haPh = haT + (size_t)b * HA_B + (size_t)c * HA_C
                      + (size_t)(h0 >> 2) * HA_HG + a * 4;
    float4 g[4], m[4];
    #pragma unroll
    for (int j = 0; j < 4; ++j) g[j] = *(const float4*)(haPh + j * HA_HG);

    // stage hp row + wc row into LDS (coalesced)
    for (int i = tid; i < Hh; i += 256) {
        hp_s[i] = hp_all[(size_t)bp * Hh + i];
        wc_s[i] = Wout[(size_t)c * Hh + i];
    }
    if (tid < Ss) {
        int any = 0;
        if (att[b * Ss + tid] > 0) {
            const int* ngp = ng + (size_t)bp * Cc * Ss + tid;
            #pragma unroll
            for (int cc = 0; cc < Cc; ++cc) any |= ngp[cc * Ss];
        }
        maskneg[tid] = any ? 0.0f : NEGV;
    }
    __syncthreads();

    // wave 0: sumW[c]
    if (tid < 64) {
        float s = 0.f;
        #pragma unroll
        for (int i = 0; i < Hh / 64; ++i) s += wc_s[tid + i * 64];
        #pragma unroll
        for (int off = 32; off; off >>= 1) s += __shfl_xor(s, off, 64);
        if (tid == 0) swr_s = s;
    }

    float ac0 = 0.f, ac1 = 0.f, ac2 = 0.f, ac3 = 0.f;
    #pragma unroll 2
    for (int it = 0; it < 24; ++it) {
        const int itn = (it + 1 < 24) ? it + 1 : 0;   // last prefetch wraps (harmless)
        #pragma unroll
        for (int j = 0; j < 4; ++j) m[j] = *(const float4*)(haPh + (itn * 4 + j) * HA_HG);
        #pragma unroll
        for (int j = 0; j < 4; ++j) {
            const int hx = h0 + it * 16 + j * 4;
            float4 p = *(const float4*)(hp_s + hx);   // LDS broadcast (wave-uniform addr)
            float4 w = *(const float4*)(wc_s + hx);
            float r0 = __builtin_amdgcn_rcpf(__builtin_amdgcn_exp2f(p.x + g[j].x) + 1.0f);
            float r1 = __builtin_amdgcn_rcpf(__builtin_amdgcn_exp2f(p.y + g[j].y) + 1.0f);
            float r2 = __builtin_amdgcn_rcpf(__builtin_amdgcn_exp2f(p.z + g[j].z) + 1.0f);
            float r3 = __builtin_amdgcn_rcpf(__builtin_amdgcn_exp2f(p.w + g[j].w) + 1.0f);
            ac0 = fmaf(w.x, r0, ac0);
            ac1 = fmaf(w.y, r1, ac1);
            ac2 = fmaf(w.z, r2, ac2);
            ac3 = fmaf(w.w, r3, ac3);
        }
        #pragma unroll
        for (int j = 0; j < 4; ++j) g[j] = m[j];
    }
    const float psum = (ac0 + ac1) + (ac2 + ac3);
    if (hh == 1) partial[a] = psum;
    __syncthreads();

    float logit = 0.f;
    if (hh == 0) {
        logit = swr_s - 2.0f * (psum + partial[a]) + maskneg[a];
        out_logits[((size_t)bp * Cc + c) * Ss + a] = logit;
        float mx = logit;
        #pragma unroll
        for (int off = 32; off; off >>= 1) mx = fmaxf(mx, __shfl_xor(mx, off, 64));
        if (lane == 0) redmax[tid >> 6] = mx;
    }
    __syncthreads();

    if (hh == 0) {
        const float rm = fmaxf(redmax[0], redmax[1]);
        const float e  = __builtin_amdgcn_exp2f((logit - rm) * 1.4426950408889634f);
        const float tg = target[((size_t)bp * Cc + c) * Ss + a];
        float se = e, st = tg, sx = tg * logit;
        #pragma unroll
        for (int off = 32; off; off >>= 1) {
            se += __shfl_xor(se, off, 64);
            st += __shfl_xor(st, off, 64);
            sx += __shfl_xor(sx, off, 64);
        }
        if (lane == 0) { red3[tid >> 6][0] = se; red3[tid >> 6][1] = st; red3[tid >> 6][2] = sx; }
    }
    __syncthreads();

    if (tid == 0) {
        const float rm = fmaxf(redmax[0], redmax[1]);
        const float SE = red3[0][0] + red3[1][0];
        const float ST = red3[0][1] + red3[1][1];
        const float SX = red3[0][2] + red3[1][2];
        const float lse = rm + __builtin_amdgcn_logf(SE) * 0.6931471805599453f;
        atomicAdd(&accum[0], lse * ST - SX);
        atomicAdd(&accum[1], ST);
        __threadfence();
        const unsigned old = atomicAdd((unsigned*)(accum + 2), 1u);
        if (old == (unsigned)(Mm * Cc - 1)) {       // last block: finalize loss
            const float n = atomicAdd(&accum[0], 0.0f);
            const float d = atomicAdd(&accum[1], 0.0f);
            out_loss[0] = n / d;
        }
    }
}

extern "C" void kernel_launch(void* const* d_in, const int* in_sizes, int n_in,
                              void* d_out, int out_size, void* d_ws, size_t ws_size,
                              hipStream_t stream) {
    const float* seq    = (const float*)d_in[0];
    const int*   att    = (const int*)  d_in[1];
    const int*   ng     = (const int*)  d_in[2];
    const float* target = (const float*)d_in[3];
    const float* Wprd   = (const float*)d_in[4];
    const float* bprd   = (const float*)d_in[5];
    const float* Warg   = (const float*)d_in[6];
    const float* barg   = (const float*)d_in[7];
    const float* Wout   = (const float*)d_in[8];

    float* out    = (float*)d_out;
    float* hp_out = (float*)d_ws;                        // 256*768 floats
    float* haT    = hp_out + (size_t)Mm * Hh;            // 2*491520 floats
    float* accum  = haT + 2 * (size_t)HA_B;              // 3 slots

    gemm_mfma<<<dim3(4, 144), 256, 0, stream>>>(seq, Wprd, Warg, bprd, barg,
                                                hp_out, haT, accum);
    biaffine_loss<<<dim3(Mm * Cc), 256, 0, stream>>>(hp_out, haT, Wout, ng, att, target,
                                                     out + 1, accum, out);
}